// Round 1
// baseline (509.426 us; speedup 1.0000x reference)
//
#include <hip/hip_runtime.h>

#pragma clang fp contract(off)

#define NB 32
#define NP 2048
#define NT 128
#define BIGF 1e30f
#define NTH 512
#define NW (NTH / 64)

// Exact replication of the reference cost formula (float32, no FMA contraction).
__device__ __forceinline__ float box_cost(float ox0, float oy0, float ox1, float oy1,
                                          float tx0, float ty0, float tx1, float ty1,
                                          float area1, float area2) {
    float l1 = ((fabsf(ox0 - tx0) + fabsf(oy0 - ty0)) + fabsf(ox1 - tx1)) + fabsf(oy1 - ty1);
    float ltx = fmaxf(ox0, tx0), lty = fmaxf(oy0, ty0);
    float rbx = fminf(ox1, tx1), rby = fminf(oy1, ty1);
    float wx = fmaxf(rbx - ltx, 0.0f), wy = fmaxf(rby - lty, 0.0f);
    float inter = wx * wy;
    float uni = (area1 + area2) - inter;
    float iou = inter / (uni + 1e-8f);
    float ex = fmaxf(fmaxf(ox1, tx1) - fminf(ox0, tx0), 0.0f);
    float ey = fmaxf(fmaxf(oy1, ty1) - fminf(oy0, ty0), 0.0f);
    float earea = ex * ey;
    float giou = iou - (earea - uni) / (earea + 1e-8f);
    return l1 - giou;  // COST_BBOX=1, COST_GIOU=1
}

// Phase 1: cost_T[b][t][p]  (rows = targets, cols = preds), [NB][NT][NP] f32.
__global__ __launch_bounds__(256) void cost_kernel(const float* __restrict__ ob,
                                                   const float* __restrict__ tb,
                                                   float* __restrict__ cost) {
    int idx = blockIdx.x * 256 + threadIdx.x;   // < NB*NT*NP
    int b = idx >> 18;                          // / (NT*NP)
    int t = (idx >> 11) & (NT - 1);
    int p = idx & (NP - 1);
    float4 o = ((const float4*)ob)[b * NP + p];
    float4 g = ((const float4*)tb)[b * NT + t];
    float a1 = (o.z - o.x) * (o.w - o.y);
    float a2 = (g.z - g.x) * (g.w - g.y);
    cost[idx] = box_cost(o.x, o.y, o.z, o.w, g.x, g.y, g.z, g.w, a1, a2);
}

// Phase 2: per-batch Jonker-Volgenant LSAP, one block per batch.
template <bool USE_WS>
__global__ __launch_bounds__(NTH) void solve_kernel(const float* __restrict__ ob,
                                                    const float* __restrict__ tb,
                                                    const float* __restrict__ cost,
                                                    int* __restrict__ out) {
    __shared__ float v[NP], spc[NP];
    __shared__ int path[NP], row4col[NP];
    __shared__ unsigned char SC[NP];
    __shared__ float u[NT];
    __shared__ int col4row[NT];
    __shared__ unsigned char SR[NT];
    __shared__ float rv[NW];
    __shared__ int ri[NW];
    __shared__ int s_cur, s_sink;
    __shared__ float s_minv;
    // recompute-path extras (1-element when unused)
    __shared__ float px0[USE_WS ? 1 : NP], py0[USE_WS ? 1 : NP];
    __shared__ float px1[USE_WS ? 1 : NP], py1[USE_WS ? 1 : NP];
    __shared__ float pa[USE_WS ? 1 : NP];
    __shared__ float tx0[USE_WS ? 1 : NT], ty0[USE_WS ? 1 : NT];
    __shared__ float tx1[USE_WS ? 1 : NT], ty1[USE_WS ? 1 : NT];
    __shared__ float tareas[USE_WS ? 1 : NT];

    const int tid = threadIdx.x;
    const int b = blockIdx.x;
    const float* costb = USE_WS ? (cost + (size_t)b * NT * NP) : nullptr;

    for (int j = tid; j < NP; j += NTH) { v[j] = 0.0f; row4col[j] = -1; }
    for (int t = tid; t < NT; t += NTH) { u[t] = 0.0f; col4row[t] = -1; }
    if (!USE_WS) {
        for (int j = tid; j < NP; j += NTH) {
            float4 o = ((const float4*)ob)[b * NP + j];
            px0[j] = o.x; py0[j] = o.y; px1[j] = o.z; py1[j] = o.w;
            pa[j] = (o.z - o.x) * (o.w - o.y);
        }
        for (int t = tid; t < NT; t += NTH) {
            float4 g = ((const float4*)tb)[b * NT + t];
            tx0[t] = g.x; ty0[t] = g.y; tx1[t] = g.z; ty1[t] = g.w;
            tareas[t] = (g.z - g.x) * (g.w - g.y);
        }
    }
    __syncthreads();

    for (int i = 0; i < NT; ++i) {
        for (int j = tid; j < NP; j += NTH) { spc[j] = BIGF; SC[j] = 0; }
        for (int t = tid; t < NT; t += NTH) SR[t] = 0;
        if (tid == 0) { s_cur = i; s_minv = 0.0f; s_sink = -1; }
        __syncthreads();

        while (s_sink < 0) {
            const int cur = s_cur;
            const float minv = s_minv;
            if (tid == 0) SR[cur] = 1;
            const float ucur = u[cur];
            float ctx0 = 0, cty0 = 0, ctx1 = 0, cty1 = 0, cta = 0;
            if (!USE_WS) {
                ctx0 = tx0[cur]; cty0 = ty0[cur];
                ctx1 = tx1[cur]; cty1 = ty1[cur]; cta = tareas[cur];
            }
            float bv = BIGF;
            int bi = NP;
            for (int k = 0; k < NP / NTH; ++k) {
                int j = tid + k * NTH;
                float cj;
                if (USE_WS) {
                    cj = costb[cur * NP + j];
                } else {
                    cj = box_cost(px0[j], py0[j], px1[j], py1[j],
                                  ctx0, cty0, ctx1, cty1, pa[j], cta);
                }
                float cand;
                if (!SC[j]) {
                    float red = ((minv + cj) - ucur) - v[j];
                    if (red < spc[j]) { spc[j] = red; path[j] = cur; }
                    cand = spc[j];
                } else {
                    cand = BIGF;
                }
                if (cand < bv || (cand == bv && j < bi)) { bv = cand; bi = j; }
            }
            // wave-level (val,idx) min, first-index tie-break
            for (int off = 32; off >= 1; off >>= 1) {
                float ov = __shfl_xor(bv, off);
                int oi = __shfl_xor(bi, off);
                if (ov < bv || (ov == bv && oi < bi)) { bv = ov; bi = oi; }
            }
            if ((tid & 63) == 0) { rv[tid >> 6] = bv; ri[tid >> 6] = bi; }
            __syncthreads();
            if (tid == 0) {
                float mv = rv[0]; int mj = ri[0];
                for (int w = 1; w < NW; ++w) {
                    if (rv[w] < mv || (rv[w] == mv && ri[w] < mj)) { mv = rv[w]; mj = ri[w]; }
                }
                s_minv = mv;
                SC[mj] = 1;
                int r = row4col[mj];
                if (r < 0) s_sink = mj; else s_cur = r;
            }
            __syncthreads();
        }

        const float minv = s_minv;
        const int sink = s_sink;
        // dual updates (pre-augment matching, exactly as reference)
        for (int j = tid; j < NP; j += NTH) {
            if (SC[j]) v[j] = (v[j] + spc[j]) - minv;
        }
        for (int t = tid; t < NT; t += NTH) {
            if (t == i) u[t] = u[t] + minv;
            else if (SR[t]) u[t] = (u[t] + minv) - spc[col4row[t]];
        }
        __syncthreads();
        if (tid == 0) {
            int j = sink;
            while (true) {
                int ii = path[j];
                row4col[j] = ii;
                int nj = col4row[ii];
                col4row[ii] = j;
                if (ii == i) break;
                j = nj;
            }
        }
        __syncthreads();
    }

    // Output: sort targets by assigned pred index (values are distinct).
    if (tid < NT) {
        int c = col4row[tid];
        int rank = 0;
        for (int t2 = 0; t2 < NT; ++t2) rank += (col4row[t2] < c) ? 1 : 0;
        out[(b * 2 + 0) * NT + rank] = c;
        out[(b * 2 + 1) * NT + rank] = tid;
    }
}

extern "C" void kernel_launch(void* const* d_in, const int* in_sizes, int n_in,
                              void* d_out, int out_size, void* d_ws, size_t ws_size,
                              hipStream_t stream) {
    const float* ob = (const float*)d_in[0];   // [32, 2048, 4] f32
    const float* tb = (const float*)d_in[1];   // [32, 128, 4] f32
    int* out = (int*)d_out;                    // [32, 2, 128] int32

    const size_t need = (size_t)NB * NT * NP * sizeof(float);  // 32 MB
    if (ws_size >= need) {
        float* cost = (float*)d_ws;
        cost_kernel<<<(NB * NT * NP) / 256, 256, 0, stream>>>(ob, tb, cost);
        solve_kernel<true><<<NB, NTH, 0, stream>>>(ob, tb, cost, out);
    } else {
        solve_kernel<false><<<NB, NTH, 0, stream>>>(ob, tb, nullptr, out);
    }
}

// Round 2
// 447.326 us; speedup vs baseline: 1.1388x; 1.1388x over previous
//
#include <hip/hip_runtime.h>

#pragma clang fp contract(off)

#define NB 32
#define NP 2048
#define NT 128
#define BIGF 1e30f
#define NSLOT 32   // per-lane column slots: 8 float4 groups * 4

// Exact replication of the reference cost formula (float32, no FMA contraction).
__device__ __forceinline__ float box_cost(float ox0, float oy0, float ox1, float oy1,
                                          float tx0, float ty0, float tx1, float ty1,
                                          float area1, float area2) {
    float l1 = ((fabsf(ox0 - tx0) + fabsf(oy0 - ty0)) + fabsf(ox1 - tx1)) + fabsf(oy1 - ty1);
    float ltx = fmaxf(ox0, tx0), lty = fmaxf(oy0, ty0);
    float rbx = fminf(ox1, tx1), rby = fminf(oy1, ty1);
    float wx = fmaxf(rbx - ltx, 0.0f), wy = fmaxf(rby - lty, 0.0f);
    float inter = wx * wy;
    float uni = (area1 + area2) - inter;
    float iou = inter / (uni + 1e-8f);
    float ex = fmaxf(fmaxf(ox1, tx1) - fminf(ox0, tx0), 0.0f);
    float ey = fmaxf(fmaxf(oy1, ty1) - fminf(oy0, ty0), 0.0f);
    float earea = ex * ey;
    float giou = iou - (earea - uni) / (earea + 1e-8f);
    return l1 - giou;
}

// Phase 1: cost_T[b][t][p] (rows = targets, cols = preds), [NB][NT][NP] f32.
__global__ __launch_bounds__(256) void cost_kernel(const float* __restrict__ ob,
                                                   const float* __restrict__ tb,
                                                   float* __restrict__ cost) {
    int idx = blockIdx.x * 256 + threadIdx.x;
    int b = idx >> 18;
    int t = (idx >> 11) & (NT - 1);
    int p = idx & (NP - 1);
    float4 o = ((const float4*)ob)[b * NP + p];
    float4 g = ((const float4*)tb)[b * NT + t];
    float a1 = (o.z - o.x) * (o.w - o.y);
    float a2 = (g.z - g.x) * (g.w - g.y);
    cost[idx] = box_cost(o.x, o.y, o.z, o.w, g.x, g.y, g.z, g.w, a1, a2);
}

// Phase 2: wave-synchronous JV LSAP. One 64-lane wave per batch.
// Column j (0..2047): owner lane = (j>>2)&63, group = j>>8, sub = j&3,
// per-lane slot s = group*4+sub. Lane holds 4 consecutive columns per group
// so row loads are 8x global_load_dwordx4, perfectly coalesced.
__global__ __launch_bounds__(64) void solve_wave(const float* __restrict__ cost,
                                                 int* __restrict__ out) {
    __shared__ int row4col[NP];
    __shared__ int col4row[NT];

    const int lane = threadIdx.x;
    const int b = blockIdx.x;
    const float* costb = cost + (size_t)b * NT * NP;

    float v_r[NSLOT], spc_r[NSLOT], cost_r[NSLOT], pf_r[NSLOT];
    int path_r[NSLOT];
    unsigned SCm;
    float u0 = 0.0f, u1 = 0.0f, pm0 = 0.0f, pm1 = 0.0f;

#pragma unroll
    for (int s = 0; s < NSLOT; ++s) { v_r[s] = 0.0f; path_r[s] = 0; }
    for (int j = lane; j < NP; j += 64) row4col[j] = -1;
    col4row[lane] = -1;
    col4row[lane + 64] = -1;

    // prefetch row 0
    {
        const float4* r0 = (const float4*)costb;
#pragma unroll
        for (int g = 0; g < 8; ++g) {
            float4 t = r0[g * 64 + lane];
            pf_r[g * 4 + 0] = t.x; pf_r[g * 4 + 1] = t.y;
            pf_r[g * 4 + 2] = t.z; pf_r[g * 4 + 3] = t.w;
        }
    }
    __syncthreads();

    for (int i = 0; i < NT; ++i) {
        // consume prefetch, issue next row's prefetch
#pragma unroll
        for (int s = 0; s < NSLOT; ++s) cost_r[s] = pf_r[s];
        if (i + 1 < NT) {
            const float4* nrow = (const float4*)(costb + (size_t)(i + 1) * NP);
#pragma unroll
            for (int g = 0; g < 8; ++g) {
                float4 t = nrow[g * 64 + lane];
                pf_r[g * 4 + 0] = t.x; pf_r[g * 4 + 1] = t.y;
                pf_r[g * 4 + 2] = t.z; pf_r[g * 4 + 3] = t.w;
            }
        }
#pragma unroll
        for (int s = 0; s < NSLOT; ++s) spc_r[s] = BIGF;
        SCm = 0u;
        int sr01 = 0;
        int cur = i;
        float mv = 0.0f;
        float us0 = (i >> 6) ? u1 : u0;
        float ucur = __shfl(us0, i & 63);
        int sink = -1;

        while (true) {
            // update shortest-path costs + local argmin (first-index tie-break)
            float bv = BIGF;
            int bj = NP;
#pragma unroll
            for (int g = 0; g < 8; ++g) {
#pragma unroll
                for (int q = 0; q < 4; ++q) {
                    const int s = g * 4 + q;
                    float red = ((mv + cost_r[s]) - ucur) - v_r[s];
                    bool notSC = ((SCm >> s) & 1u) == 0u;
                    bool imp = notSC && (red < spc_r[s]);
                    if (imp) { spc_r[s] = red; path_r[s] = cur; }
                    float cand = notSC ? spc_r[s] : BIGF;
                    int j = g * 256 + lane * 4 + q;
                    if (cand < bv) { bv = cand; bj = j; }
                }
            }
            // 64-lane butterfly min, tie-break on smaller global index
#pragma unroll
            for (int off = 32; off >= 1; off >>= 1) {
                float ov = __shfl_xor(bv, off);
                int oj = __shfl_xor(bj, off);
                if (ov < bv || (ov == bv && oj < bj)) { bv = ov; bj = oj; }
            }
            mv = bv;
            const int mj = bj;
            // mark SC on owner lane
            if (((mj >> 2) & 63) == lane) SCm |= (1u << (((mj >> 8) << 2) | (mj & 3)));
            int r = row4col[mj];  // broadcast LDS read (uniform addr)
            if (r < 0) { sink = mj; break; }
            // row r was popped: record SR + frozen spc (== mv at pop) on owner lane
            if ((r & 63) == lane) {
                if (r < 64) { sr01 |= 1; pm0 = mv; }
                else        { sr01 |= 2; pm1 = mv; }
            }
            cur = r;
            float us = (r >> 6) ? u1 : u0;
            ucur = __shfl(us, r & 63);
            // load cost row r (L2-warm: visited rows were read before)
            int rs = __builtin_amdgcn_readfirstlane(r);
            const float4* rrow = (const float4*)(costb + (size_t)rs * NP);
#pragma unroll
            for (int g = 0; g < 8; ++g) {
                float4 t = rrow[g * 64 + lane];
                cost_r[g * 4 + 0] = t.x; cost_r[g * 4 + 1] = t.y;
                cost_r[g * 4 + 2] = t.z; cost_r[g * 4 + 3] = t.w;
            }
        }

        const float minv = mv;
        // dual updates (exact reference order)
        if ((i & 63) == lane) { if (i < 64) u0 = u0 + minv; else u1 = u1 + minv; }
        if (sr01 & 1) u0 = (u0 + minv) - pm0;
        if (sr01 & 2) u1 = (u1 + minv) - pm1;
#pragma unroll
        for (int s = 0; s < NSLOT; ++s) {
            if ((SCm >> s) & 1u) v_r[s] = (v_r[s] + spc_r[s]) - minv;
        }

        // augment along alternating path (uniform control, path via select chain)
        int j = sink;
        while (true) {
            int slot = ((j >> 8) << 2) | (j & 3);
            int pv = path_r[0];
#pragma unroll
            for (int s = 1; s < NSLOT; ++s) pv = (slot == s) ? path_r[s] : pv;
            int ii = __shfl(pv, (j >> 2) & 63);
            if (lane == 0) row4col[j] = ii;
            int nj = col4row[ii];
            if (lane == 0) col4row[ii] = j;
            if (ii == i) break;
            j = nj;
        }
        __syncthreads();  // single wave: cheap; orders lane0 LDS writes for next row
    }

    // output: sort targets by assigned pred index (all distinct)
    __syncthreads();
    for (int t = lane; t < NT; t += 64) {
        int c = col4row[t];
        int rank = 0;
        for (int t2 = 0; t2 < NT; ++t2) rank += (col4row[t2] < c) ? 1 : 0;
        out[(b * 2 + 0) * NT + rank] = c;
        out[(b * 2 + 1) * NT + rank] = t;
    }
}

// Fallback (ws too small): LDS-based block solver computing costs on the fly.
__global__ __launch_bounds__(512) void solve_fallback(const float* __restrict__ ob,
                                                      const float* __restrict__ tb,
                                                      int* __restrict__ out) {
    __shared__ float v[NP], spc[NP];
    __shared__ int path[NP], row4col[NP];
    __shared__ unsigned char SC[NP];
    __shared__ float u[NT];
    __shared__ int col4row[NT];
    __shared__ unsigned char SR[NT];
    __shared__ float rv[8];
    __shared__ int ri[8];
    __shared__ int s_cur, s_sink;
    __shared__ float s_minv;
    __shared__ float px0[NP], py0[NP], px1[NP], py1[NP], pa[NP];
    __shared__ float tx0[NT], ty0[NT], tx1[NT], ty1[NT], ta[NT];

    const int tid = threadIdx.x;
    const int b = blockIdx.x;

    for (int j = tid; j < NP; j += 512) {
        v[j] = 0.0f; row4col[j] = -1;
        float4 o = ((const float4*)ob)[b * NP + j];
        px0[j] = o.x; py0[j] = o.y; px1[j] = o.z; py1[j] = o.w;
        pa[j] = (o.z - o.x) * (o.w - o.y);
    }
    for (int t = tid; t < NT; t += 512) {
        u[t] = 0.0f; col4row[t] = -1;
        float4 g = ((const float4*)tb)[b * NT + t];
        tx0[t] = g.x; ty0[t] = g.y; tx1[t] = g.z; ty1[t] = g.w;
        ta[t] = (g.z - g.x) * (g.w - g.y);
    }
    __syncthreads();

    for (int i = 0; i < NT; ++i) {
        for (int j = tid; j < NP; j += 512) { spc[j] = BIGF; SC[j] = 0; }
        for (int t = tid; t < NT; t += 512) SR[t] = 0;
        if (tid == 0) { s_cur = i; s_minv = 0.0f; s_sink = -1; }
        __syncthreads();

        while (s_sink < 0) {
            const int cur = s_cur;
            const float minv = s_minv;
            if (tid == 0) SR[cur] = 1;
            const float ucur = u[cur];
            float c0 = tx0[cur], c1 = ty0[cur], c2 = tx1[cur], c3 = ty1[cur], ca = ta[cur];
            float bv = BIGF;
            int bi = NP;
            for (int k = 0; k < NP / 512; ++k) {
                int j = tid + k * 512;
                float cj = box_cost(px0[j], py0[j], px1[j], py1[j], c0, c1, c2, c3, pa[j], ca);
                float cand;
                if (!SC[j]) {
                    float red = ((minv + cj) - ucur) - v[j];
                    if (red < spc[j]) { spc[j] = red; path[j] = cur; }
                    cand = spc[j];
                } else {
                    cand = BIGF;
                }
                if (cand < bv || (cand == bv && j < bi)) { bv = cand; bi = j; }
            }
            for (int off = 32; off >= 1; off >>= 1) {
                float ov = __shfl_xor(bv, off);
                int oi = __shfl_xor(bi, off);
                if (ov < bv || (ov == bv && oi < bi)) { bv = ov; bi = oi; }
            }
            if ((tid & 63) == 0) { rv[tid >> 6] = bv; ri[tid >> 6] = bi; }
            __syncthreads();
            if (tid == 0) {
                float mvv = rv[0]; int mjj = ri[0];
                for (int w = 1; w < 8; ++w)
                    if (rv[w] < mvv || (rv[w] == mvv && ri[w] < mjj)) { mvv = rv[w]; mjj = ri[w]; }
                s_minv = mvv;
                SC[mjj] = 1;
                int r = row4col[mjj];
                if (r < 0) s_sink = mjj; else s_cur = r;
            }
            __syncthreads();
        }

        const float minv = s_minv;
        const int sink = s_sink;
        for (int j = tid; j < NP; j += 512) if (SC[j]) v[j] = (v[j] + spc[j]) - minv;
        for (int t = tid; t < NT; t += 512) {
            if (t == i) u[t] = u[t] + minv;
            else if (SR[t]) u[t] = (u[t] + minv) - spc[col4row[t]];
        }
        __syncthreads();
        if (tid == 0) {
            int j = sink;
            while (true) {
                int ii = path[j];
                row4col[j] = ii;
                int nj = col4row[ii];
                col4row[ii] = j;
                if (ii == i) break;
                j = nj;
            }
        }
        __syncthreads();
    }

    if (tid < NT) {
        int c = col4row[tid];
        int rank = 0;
        for (int t2 = 0; t2 < NT; ++t2) rank += (col4row[t2] < c) ? 1 : 0;
        out[(b * 2 + 0) * NT + rank] = c;
        out[(b * 2 + 1) * NT + rank] = tid;
    }
}

extern "C" void kernel_launch(void* const* d_in, const int* in_sizes, int n_in,
                              void* d_out, int out_size, void* d_ws, size_t ws_size,
                              hipStream_t stream) {
    const float* ob = (const float*)d_in[0];   // [32, 2048, 4] f32
    const float* tb = (const float*)d_in[1];   // [32, 128, 4] f32
    int* out = (int*)d_out;                    // [32, 2, 128] int32

    const size_t need = (size_t)NB * NT * NP * sizeof(float);  // 32 MB
    if (ws_size >= need) {
        float* cost = (float*)d_ws;
        cost_kernel<<<(NB * NT * NP) / 256, 256, 0, stream>>>(ob, tb, cost);
        solve_wave<<<NB, 64, 0, stream>>>(cost, out);
    } else {
        solve_fallback<<<NB, 512, 0, stream>>>(ob, tb, out);
    }
}